// Round 2
// baseline (74.678 us; speedup 1.0000x reference)
//
#include <hip/hip_runtime.h>

// BPS tokenizer: per (batch, basis point) argmin_n |pc[b,n]-basis[p]|^2,
// output [dist, dx, dy, dz]. B=16, N=4096, P=4096.
//
// Structure: 256 blocks (16 b x 16 ptiles) x 1024 threads.
// Thread (pl, g) = (t&63, t>>6) handles 4 basis points p = ptile*256 + 64q + pl
// over N-range [g*256, (g+1)*256). Cloud staged once in LDS as
// (-2x,-2y,-2z,|p|^2) so d2 = (bsq + s) + dot(scaled, basis) is bit-identical
// to the reference's (b_sq + pc_sq) - 2*cross (pow2 scale is exact).
// Min tracked per 16-pt chunk via v_min3_f32 (no index); winning chunk is
// rescanned with bit-identical ops for the first d2 == min (ref tie-break).

#define NB 16
#define NN 4096
#define NP 4096
#define PT 256             // basis points per block
#define NGRP 16            // N-split groups (= waves) per block
#define THREADS 1024
#define CH 16              // chunk size
#define NPT (NN / NGRP)    // 256 cloud points per thread
#define NCH (NPT / CH)     // 16 chunks per thread

__device__ __forceinline__ float min3f(float a, float b, float c) {
    float r;
    asm("v_min3_f32 %0, %1, %2, %3" : "=v"(r) : "v"(a), "v"(b), "v"(c));
    return r;
}

__global__ __launch_bounds__(THREADS, 4) void bps_kernel(
    const float* __restrict__ pc,     // [B, N, 3]
    const float* __restrict__ basis,  // [P, 3]
    float* __restrict__ out)          // [B, P, 4]
{
#pragma clang fp contract(off)
    __shared__ float4 cloud[NN];               // 64 KB
    __shared__ float  redv[NGRP][4][64];       // 16 KB
    __shared__ int    redi[NGRP][4][64];       // 16 KB

    const int b     = blockIdx.x >> 4;   // / (NP/PT)
    const int ptile = blockIdx.x & 15;
    const int t     = threadIdx.x;
    const int pl    = t & 63;
    const int g     = t >> 6;            // 0..15, == wave id

    // ---- stage cloud for batch b (3 float4 per thread = 4 points) ----
    {
        const float4* pc4 = (const float4*)(pc + (size_t)b * NN * 3);
        const float4 f0 = pc4[3 * t + 0];
        const float4 f1 = pc4[3 * t + 1];
        const float4 f2 = pc4[3 * t + 2];
        const float x0 = f0.x, y0 = f0.y, z0 = f0.z;
        const float x1 = f0.w, y1 = f1.x, z1 = f1.y;
        const float x2 = f1.z, y2 = f1.w, z2 = f2.x;
        const float x3 = f2.y, y3 = f2.z, z3 = f2.w;
        cloud[4*t+0] = make_float4(-2.f*x0, -2.f*y0, -2.f*z0, (x0*x0 + y0*y0) + z0*z0);
        cloud[4*t+1] = make_float4(-2.f*x1, -2.f*y1, -2.f*z1, (x1*x1 + y1*y1) + z1*z1);
        cloud[4*t+2] = make_float4(-2.f*x2, -2.f*y2, -2.f*z2, (x2*x2 + y2*y2) + z2*z2);
        cloud[4*t+3] = make_float4(-2.f*x3, -2.f*y3, -2.f*z3, (x3*x3 + y3*y3) + z3*z3);
    }

    // ---- basis registers for this thread's 4 basis points ----
    const int pbase = ptile * PT + pl;
#define DECLQ(Q) \
    const float bx##Q = basis[3*(pbase + 64*Q) + 0]; \
    const float by##Q = basis[3*(pbase + 64*Q) + 1]; \
    const float bz##Q = basis[3*(pbase + 64*Q) + 2]; \
    const float tb##Q = (bx##Q*bx##Q + by##Q*by##Q) + bz##Q*bz##Q;
    DECLQ(0) DECLQ(1) DECLQ(2) DECLQ(3)
#undef DECLQ

    __syncthreads();

    float gm0 = __builtin_inff(), gm1 = gm0, gm2 = gm0, gm3 = gm0;
    int   cb0 = 0, cb1 = 0, cb2 = 0, cb3 = 0;
    const int n0 = g * NPT;

    for (int c = 0; c < NCH; ++c) {
        const int nb = n0 + c * CH;
        float cm0, cm1, cm2, cm3;
        float pd0, pd1, pd2, pd3;
        #pragma unroll
        for (int j = 0; j < CH; ++j) {
            const float4 cp = cloud[nb + j];   // uniform addr -> broadcast
#define STEPQ(Q) { \
            const float cr = ((cp.x*bx##Q + cp.y*by##Q) + cp.z*bz##Q); \
            const float d2 = (tb##Q + cp.w) + cr; \
            if (j == 0)      cm##Q = d2; \
            else if (j & 1)  pd##Q = d2; \
            else             cm##Q = min3f(cm##Q, pd##Q, d2); }
            STEPQ(0) STEPQ(1) STEPQ(2) STEPQ(3)
#undef STEPQ
        }
        cm0 = fminf(cm0, pd0); cm1 = fminf(cm1, pd1);
        cm2 = fminf(cm2, pd2); cm3 = fminf(cm3, pd3);
        if (cm0 < gm0) { gm0 = cm0; cb0 = nb; }   // strict < keeps earliest chunk
        if (cm1 < gm1) { gm1 = cm1; cb1 = nb; }
        if (cm2 < gm2) { gm2 = cm2; cb2 = nb; }
        if (cm3 < gm3) { gm3 = cm3; cb3 = nb; }
    }

    // ---- rescan winning chunk: first index with d2 == gmin (bit-identical ops) ----
    int gi0 = -1, gi1 = -1, gi2 = -1, gi3 = -1;
    #pragma unroll
    for (int j = 0; j < CH; ++j) {
#define RESQ(Q) { \
        const float4 cp = cloud[cb##Q + j]; \
        const float cr = ((cp.x*bx##Q + cp.y*by##Q) + cp.z*bz##Q); \
        const float d2 = (tb##Q + cp.w) + cr; \
        if (gi##Q < 0 && d2 == gm##Q) gi##Q = cb##Q + j; }
        RESQ(0) RESQ(1) RESQ(2) RESQ(3)
#undef RESQ
    }

    redv[g][0][pl] = gm0; redi[g][0][pl] = gi0;
    redv[g][1][pl] = gm1; redi[g][1][pl] = gi1;
    redv[g][2][pl] = gm2; redi[g][2][pl] = gi2;
    redv[g][3][pl] = gm3; redi[g][3][pl] = gi3;

    __syncthreads();

    // ---- combine 16 groups (ascending n-order + strict <), emit output ----
    if (t < PT) {
        const int pl2 = t & 63;
        const int q   = t >> 6;
        float bm = redv[0][q][pl2];
        int   bi = redi[0][q][pl2];
        #pragma unroll
        for (int gg = 1; gg < NGRP; ++gg) {
            const float v = redv[gg][q][pl2];
            const int   i = redi[gg][q][pl2];
            if (v < bm) { bm = v; bi = i; }
        }
        const int p  = ptile * PT + q * 64 + pl2;
        const float bx = basis[3*p+0], by = basis[3*p+1], bz = basis[3*p+2];
        const float4 c = cloud[bi];
        const float nx = -0.5f * c.x, ny = -0.5f * c.y, nz = -0.5f * c.z;  // exact
        const float dx = nx - bx, dy = ny - by, dz = nz - bz;
        const float dist = sqrtf((dx*dx + dy*dy) + dz*dz);
        ((float4*)out)[(size_t)b * NP + p] = make_float4(dist, dx, dy, dz);
    }
}

extern "C" void kernel_launch(void* const* d_in, const int* in_sizes, int n_in,
                              void* d_out, int out_size, void* d_ws, size_t ws_size,
                              hipStream_t stream) {
    const float* pc    = (const float*)d_in[0];  // [16, 4096, 3]
    const float* basis = (const float*)d_in[1];  // [4096, 3]
    float* out = (float*)d_out;                  // [16, 4096, 4]

    dim3 grid(NB * (NP / PT));  // 256 blocks
    dim3 block(THREADS);
    bps_kernel<<<grid, block, 0, stream>>>(pc, basis, out);
}

// Round 3
// 28.993 us; speedup vs baseline: 2.5757x; 2.5757x over previous
//
#include <hip/hip_runtime.h>

// BPS tokenizer: per (batch, basis) argmin_n |pc[b,n]-basis[p]|^2 -> [dist,dx,dy,dz].
// B=16, N=4096, P=4096. 256 blocks x 1024 threads, one block per (b, 256-basis tile).
//
// Cloud staged in LDS as pair-SoA: pair (2j,2j+1) -> {-2x0,-2x1,-2y0,-2y1}{-2z0,-2z1,w0,w1},
// w = |p|^2. argmin key = fma(-2x,bx, fma(-2y,by, fma(-2z,bz, w))) = d2 - |b|^2 (same argmin).
// Main loop: v_pk_fma_f32 on packed pairs (2 pts/instr), v_min3 chunk-min (16-pt chunks),
// per-chunk (min, chunkId) tracking. Chunk slots rotated by chunk&7 so the final
// (post-reduction, 256-thread) rescan's divergent reads spread across banks.
// Rescan recomputes the identical fma chain -> exact equality match, first-index tie-break.

typedef __attribute__((ext_vector_type(2))) float f32x2;

#define NB 16
#define NN 4096
#define NP 4096
#define PT 256
#define NGRP 16           // waves per block; each scans 256 points = 16 chunks
#define THREADS 1024

__device__ __forceinline__ float min3f(float a, float b, float c) {
    float r;
    asm("v_min3_f32 %0, %1, %2, %3" : "=v"(r) : "v"(a), "v"(b), "v"(c));
    return r;
}
__device__ __forceinline__ f32x2 pk_fma(f32x2 a, f32x2 b, f32x2 c) {
    f32x2 d;
    asm("v_pk_fma_f32 %0, %1, %2, %3" : "=v"(d) : "v"(a), "v"(b), "v"(c));
    return d;
}
__device__ __forceinline__ int pslot(int p) {  // rotate pair within its 8-pair chunk
    return (p & ~7) | (((p & 7) + ((p >> 3) & 7)) & 7);
}

__global__ __launch_bounds__(THREADS, 4) void bps_kernel(
    const float* __restrict__ pc,     // [B, N, 3]
    const float* __restrict__ basis,  // [P, 3]
    float* __restrict__ out)          // [B, P, 4]
{
#pragma clang fp contract(off)
    __shared__ float4 cloudP[NN];            // 64 KB: 2048 pairs x 32B
    __shared__ float  redv[NGRP][4][64];     // 16 KB
    __shared__ int    redi[NGRP][4][64];     // 16 KB

    const int b     = blockIdx.x >> 4;
    const int ptile = blockIdx.x & 15;
    const int t     = threadIdx.x;
    const int pl    = t & 63;
    const int g     = t >> 6;                // wave id 0..15

    // ---- stage 4 points -> 2 rotated pair-SoA blocks ----
    {
        const float4* pc4 = (const float4*)(pc + (size_t)b * NN * 3);
        const float4 f0 = pc4[3*t+0], f1 = pc4[3*t+1], f2 = pc4[3*t+2];
        const float X[4] = {f0.x, f0.w, f1.z, f2.y};
        const float Y[4] = {f0.y, f1.x, f1.w, f2.z};
        const float Z[4] = {f0.z, f1.y, f2.x, f2.w};
        float W[4];
        #pragma unroll
        for (int j = 0; j < 4; ++j) W[j] = (X[j]*X[j] + Y[j]*Y[j]) + Z[j]*Z[j];
        #pragma unroll
        for (int pr = 0; pr < 2; ++pr) {
            const int j0 = 2*pr, j1 = 2*pr + 1;
            const int sl = pslot(2*t + pr);
            cloudP[2*sl]   = make_float4(-2.f*X[j0], -2.f*X[j1], -2.f*Y[j0], -2.f*Y[j1]);
            cloudP[2*sl+1] = make_float4(-2.f*Z[j0], -2.f*Z[j1], W[j0], W[j1]);
        }
    }

    // ---- packed basis registers for 4 basis points ----
    const int pbase = (ptile << 8) + pl;
#define DECLQ(Q) \
    const float bxs##Q = basis[3*(pbase + 64*Q) + 0]; \
    const float bys##Q = basis[3*(pbase + 64*Q) + 1]; \
    const float bzs##Q = basis[3*(pbase + 64*Q) + 2]; \
    const f32x2 bxx##Q = {bxs##Q, bxs##Q}; \
    const f32x2 byy##Q = {bys##Q, bys##Q}; \
    const f32x2 bzz##Q = {bzs##Q, bzs##Q};
    DECLQ(0) DECLQ(1) DECLQ(2) DECLQ(3)
#undef DECLQ

    __syncthreads();

    float gm0 = __builtin_inff(), gm1 = gm0, gm2 = gm0, gm3 = gm0;
    int   cb0 = 0, cb1 = 0, cb2 = 0, cb3 = 0;

    for (int c = 0; c < 16; ++c) {
        const int C = (g << 4) + c;              // global chunk id 0..255
        const float4* chunk = cloudP + (C << 4); // 16 float4 per chunk
        float cm0, cm1, cm2, cm3;
        #pragma unroll
        for (int s = 0; s < 8; ++s) {
            const float4 A1 = chunk[2*s];        // uniform addr -> broadcast
            const float4 A2 = chunk[2*s+1];
            const f32x2 xs = {A1.x, A1.y};
            const f32x2 ys = {A1.z, A1.w};
            const f32x2 zs = {A2.x, A2.y};
            const f32x2 ws = {A2.z, A2.w};
#define STEPQ(Q) { \
            const f32x2 k = pk_fma(xs, bxx##Q, pk_fma(ys, byy##Q, pk_fma(zs, bzz##Q, ws))); \
            if (s == 0) cm##Q = fminf(k.x, k.y); \
            else        cm##Q = min3f(cm##Q, k.x, k.y); }
            STEPQ(0) STEPQ(1) STEPQ(2) STEPQ(3)
#undef STEPQ
        }
        if (cm0 < gm0) { gm0 = cm0; cb0 = C; }   // strict < keeps earliest chunk
        if (cm1 < gm1) { gm1 = cm1; cb1 = C; }
        if (cm2 < gm2) { gm2 = cm2; cb2 = C; }
        if (cm3 < gm3) { gm3 = cm3; cb3 = C; }
    }

    redv[g][0][pl] = gm0; redi[g][0][pl] = cb0;
    redv[g][1][pl] = gm1; redi[g][1][pl] = cb1;
    redv[g][2][pl] = gm2; redi[g][2][pl] = cb2;
    redv[g][3][pl] = gm3; redi[g][3][pl] = cb3;

    __syncthreads();

    // ---- reduce 16 groups lexicographically, rescan winning chunk, emit ----
    if (t < PT) {
        const int pl2 = t & 63;
        const int q   = t >> 6;
        float bm = redv[0][q][pl2];
        int   bC = redi[0][q][pl2];
        #pragma unroll
        for (int gg = 1; gg < NGRP; ++gg) {
            const float v = redv[gg][q][pl2];
            const int   i = redi[gg][q][pl2];
            if (v < bm || (v == bm && i < bC)) { bm = v; bC = i; }
        }
        const int p  = (ptile << 8) + (q << 6) + pl2;
        const float bx = basis[3*p+0], by = basis[3*p+1], bz = basis[3*p+2];

        const float4* chunk = cloudP + (bC << 4);
        const int rot = bC & 7;
        int found = 0;
        float nx = 0.f, ny = 0.f, nz = 0.f;
        #pragma unroll
        for (int jj = 0; jj < 16; ++jj) {        // true point order for first-index
            const int s = (((jj >> 1) + rot) & 7);
            const float4 A1 = chunk[2*s];
            const float4 A2 = chunk[2*s+1];
            const int h = jj & 1;
            const float x = h ? A1.y : A1.x;
            const float y = h ? A1.w : A1.z;
            const float z = h ? A2.y : A2.x;
            const float w = h ? A2.w : A2.z;
            const float key = fmaf(x, bx, fmaf(y, by, fmaf(z, bz, w)));  // identical chain
            if (!found && key == bm) { found = 1; nx = -0.5f*x; ny = -0.5f*y; nz = -0.5f*z; }
        }
        const float dx = nx - bx, dy = ny - by, dz = nz - bz;
        const float dist = sqrtf((dx*dx + dy*dy) + dz*dz);
        ((float4*)out)[(size_t)b * NP + p] = make_float4(dist, dx, dy, dz);
    }
}

extern "C" void kernel_launch(void* const* d_in, const int* in_sizes, int n_in,
                              void* d_out, int out_size, void* d_ws, size_t ws_size,
                              hipStream_t stream) {
    const float* pc    = (const float*)d_in[0];  // [16, 4096, 3]
    const float* basis = (const float*)d_in[1];  // [4096, 3]
    float* out = (float*)d_out;                  // [16, 4096, 4]

    dim3 grid(NB * (NP / PT));  // 256 blocks
    dim3 block(THREADS);
    bps_kernel<<<grid, block, 0, stream>>>(pc, basis, out);
}